// Round 7
// baseline (349.683 us; speedup 1.0000x reference)
//
#include <hip/hip_runtime.h>

#define TT 128
#define NN 512
#define DH 64
#define EE 8192
#define LOB (18 * 8 * 64)   // uint4 count of hi-weight fragments

typedef __bf16 bf16x8 __attribute__((ext_vector_type(8)));
typedef float f32x4 __attribute__((ext_vector_type(4)));

struct US8 { unsigned short u[8]; };
struct Frag { bf16x8 hi, lo; };

static __device__ __forceinline__ unsigned short f2bf(float x) {
    union { float f; unsigned u; } c; c.f = x;
    unsigned r = (c.u + 0x7FFFu + ((c.u >> 16) & 1u)) >> 16;   // RNE
    return (unsigned short)r;
}
static __device__ __forceinline__ float bf2f(unsigned short b) {
    union { unsigned u; float f; } c; c.u = ((unsigned)b) << 16;
    return c.f;
}
// fast silu accumulate: acc + x * rcp(1 + exp(-x))
static __device__ __forceinline__ float silu_acc(float a, float b, float acc) {
    float x = a + b;
    float e = __expf(-x);
    return fmaf(x, __builtin_amdgcn_rcpf(1.0f + e), acc);
}
static __device__ __forceinline__ float silu_f(float x) {
    float e = __expf(-x);
    return x * __builtin_amdgcn_rcpf(1.0f + e);
}
// split fp32 -> hi/lo bf16 via native casts (v_cvt_pk_bf16_f32)
static __device__ __forceinline__ Frag split8(const float* v) {
    Frag f;
    #pragma unroll
    for (int i = 0; i < 8; ++i) {
        __bf16 hb = (__bf16)v[i];
        f.hi[i] = hb;
        f.lo[i] = (__bf16)(v[i] - (float)hb);
    }
    return f;
}
static __device__ __forceinline__ f32x4 mmac(bf16x8 a, uint4 bw, f32x4 c) {
    return __builtin_amdgcn_mfma_f32_16x16x32_bf16(
        a, __builtin_bit_cast(bf16x8, bw), c, 0, 0, 0);
}
static __device__ __forceinline__ f32x4 mm3(Frag a, uint4 wh, uint4 wl, f32x4 c) {
    c = mmac(a.hi, wh, c);
    c = mmac(a.lo, wh, c);
    c = mmac(a.hi, wl, c);
    return c;
}

// ---- fused setup: blocks 0-17 prepack weights; block 18 builds CSR ----
__global__ __launch_bounds__(512) void setup_kernel(
    const int* __restrict__ ei,
    const float* __restrict__ msg1_w, const float* __restrict__ msg2_w,
    const float* __restrict__ upd1_w, const float* __restrict__ upd2_w,
    uint4* __restrict__ pack,
    int* __restrict__ counts, int* __restrict__ offsets,
    int* __restrict__ ssrc) {
    int b = blockIdx.x;
    if (b < 18) {
        int l = b / 6, bi = b % 6;
        const float* W;
        if (bi == 0)      W = msg1_w + (size_t)l * 128 * 64;
        else if (bi == 1) W = msg1_w + (size_t)l * 128 * 64 + 64 * 64;
        else if (bi == 2) W = msg2_w + (size_t)l * 64 * 64;
        else if (bi == 3) W = upd1_w + (size_t)l * 128 * 64;
        else if (bi == 4) W = upd1_w + (size_t)l * 128 * 64 + 64 * 64;
        else              W = upd2_w + (size_t)l * 64 * 64;
        int lane = threadIdx.x & 63;
        int sub  = threadIdx.x >> 6;          // 0..7 = nt*2+kc
        int nt = sub >> 1, kc = sub & 1;
        US8 oh, ol;
        #pragma unroll
        for (int i = 0; i < 8; ++i) {
            int k = kc * 32 + (lane >> 4) * 8 + i;
            int col = nt * 16 + (lane & 15);
            float w = W[k * 64 + col];
            unsigned short hu = f2bf(w);
            oh.u[i] = hu;
            ol.u[i] = f2bf(w - bf2f(hu));
        }
        size_t fi = ((size_t)b * 8 + sub) * 64 + lane;
        pack[fi]       = __builtin_bit_cast(uint4, oh);
        pack[LOB + fi] = __builtin_bit_cast(uint4, ol);
        return;
    }
    // CSR build in one block, all in LDS
    __shared__ int cnt[NN];
    __shared__ int tmp[NN];
    __shared__ int cur[NN];
    int i = threadIdx.x;
    cnt[i] = 0;
    __syncthreads();
    #pragma unroll
    for (int r = 0; r < EE / 512; ++r)
        atomicAdd(&cnt[ei[EE + r * 512 + i]], 1);
    __syncthreads();
    int c = cnt[i];
    tmp[i] = c;
    __syncthreads();
    for (int off = 1; off < NN; off <<= 1) {
        int v = (i >= off) ? tmp[i - off] : 0;
        __syncthreads();
        tmp[i] += v;
        __syncthreads();
    }
    counts[i] = c;
    offsets[i + 1] = tmp[i];
    if (i == 0) offsets[0] = 0;
    cur[i] = tmp[i] - c;
    __syncthreads();
    #pragma unroll
    for (int r = 0; r < EE / 512; ++r) {
        int e = r * 512 + i;
        int dst = ei[EE + e];
        int pos = atomicAdd(&cur[dst], 1);
        ssrc[pos] = ei[e];
    }
}

// XCD-affine block mapping: all 8 blocks of one tt land on the same XCD,
// identical across encode/layer kernels so hs/hd/h stay L2-resident.
static __device__ __forceinline__ int swz_rowbase(int bid, int w) {
    int xcd = bid & 7;
    int idx = bid >> 3;                 // 0..127
    int tt  = xcd * 16 + (idx >> 3);    // 16 tt per XCD
    int sub = idx & 7;                  // 64-row chunk within tt
    return tt * NN + sub * 64 + w * 16;
}

// ---- encode + layer-0 projections (split MFMA). Wave = 16 rows. ----
__global__ __launch_bounds__(256) void encode_mfma_kernel(
    const float* __restrict__ t, const float* __restrict__ enc_w,
    const float* __restrict__ enc_b, const float* __restrict__ b1,
    const uint4* __restrict__ pack,
    float* __restrict__ h, float* __restrict__ hs, float* __restrict__ hd) {
    int lane = threadIdx.x & 63;
    int rowbase = swz_rowbase(blockIdx.x, threadIdx.x >> 6);
    int arow = lane & 15, kgrp = lane >> 4, k0 = kgrp * 8;
    int row = rowbase + arow;
    int tt = row >> 9, n = row & (NN - 1);
    float tv = t[tt];

    float hv[16];
    #pragma unroll
    for (int kc = 0; kc < 2; ++kc) {
        #pragma unroll
        for (int i = 0; i < 8; ++i) {
            int k = kc * 32 + k0 + i;
            hv[kc * 8 + i] = tv * enc_w[k] + enc_w[(1 + n) * DH + k] + enc_b[k];
        }
        *(float4*)(h + (size_t)row * DH + kc * 32 + k0) =
            make_float4(hv[kc * 8], hv[kc * 8 + 1], hv[kc * 8 + 2], hv[kc * 8 + 3]);
        *(float4*)(h + (size_t)row * DH + kc * 32 + k0 + 4) =
            make_float4(hv[kc * 8 + 4], hv[kc * 8 + 5], hv[kc * 8 + 6], hv[kc * 8 + 7]);
    }
    Frag a0 = split8(&hv[0]), a1 = split8(&hv[8]);

    const uint4* PWtH = pack;
    const uint4* PWbH = pack + 8 * 64;
    const uint4* PWtL = PWtH + LOB;
    const uint4* PWbL = PWbH + LOB;
    #pragma unroll
    for (int nt = 0; nt < 4; ++nt) {
        f32x4 s; f32x4 d;
        float b1v = b1[nt * 16 + (lane & 15)];
        #pragma unroll
        for (int r = 0; r < 4; ++r) { s[r] = 0.f; d[r] = b1v; }
        s = mm3(a0, PWtH[(nt * 2 + 0) * 64 + lane], PWtL[(nt * 2 + 0) * 64 + lane], s);
        s = mm3(a1, PWtH[(nt * 2 + 1) * 64 + lane], PWtL[(nt * 2 + 1) * 64 + lane], s);
        d = mm3(a0, PWbH[(nt * 2 + 0) * 64 + lane], PWbL[(nt * 2 + 0) * 64 + lane], d);
        d = mm3(a1, PWbH[(nt * 2 + 1) * 64 + lane], PWbL[(nt * 2 + 1) * 64 + lane], d);
        #pragma unroll
        for (int r = 0; r < 4; ++r) {
            int rr = rowbase + kgrp * 4 + r;
            hs[(size_t)rr * DH + nt * 16 + (lane & 15)] = s[r];
            hd[(size_t)rr * DH + nt * 16 + (lane & 15)] = d[r];
        }
    }
}

// ---- fused layer: agg (gather+silu, wave-private LDS) + update MLP ----
__global__ __launch_bounds__(256) void layer_kernel(
    float* __restrict__ h, const float* __restrict__ hs_in,
    float* __restrict__ hs_out, float* __restrict__ hd,
    const int* __restrict__ counts, const int* __restrict__ offsets,
    const int* __restrict__ ssrc, const uint4* __restrict__ pack, int l,
    const float* __restrict__ b2, const float* __restrict__ ub1,
    const float* __restrict__ ub2, const float* __restrict__ b1n,
    const float* __restrict__ ro_w, const float* __restrict__ ro_b,
    float* __restrict__ out, int last) {
    __shared__ float TAgg[4][16 * 68];
    __shared__ float tileA[4][16 * 68];
    __shared__ float tileB[4][16 * 68];
    int lane = threadIdx.x & 63;
    int w = threadIdx.x >> 6;
    int rowbase = swz_rowbase(blockIdx.x, w);
    int tt = rowbase >> 9;
    int nbase = rowbase & (NN - 1);
    float* TG = TAgg[w];
    float* TA = tileA[w];
    float* TB = tileB[w];
    int arow = lane & 15, kgrp = lane >> 4, k0 = kgrp * 8;
    int hrow = rowbase + arow;

    // ---- agg phase: this wave aggregates its own 16 node-rows ----
    {
        int eg = lane >> 4;                // edge slot 0..3
        int chb = (lane & 15) * 4;         // float index of this lane's float4
        int ch4 = chb * 4;                 // byte offset
        const char* hb = (const char*)(hs_in + (size_t)tt * NN * DH);
        for (int j = 0; j < 16; ++j) {
            int nn = nbase + j;
            size_t rowoff = ((size_t)tt * NN + nn) * DH;
            float4 hdv = *(const float4*)(hd + rowoff + chb);
            int beg = offsets[nn], end = offsets[nn + 1];
            float4 acc = make_float4(0.f, 0.f, 0.f, 0.f);
            int i = beg + eg;
            for (; i + 4 < end; i += 8) {
                int s0 = ssrc[i] << 8;
                int s1 = ssrc[i + 4] << 8;
                float4 v0 = *(const float4*)(hb + s0 + ch4);
                float4 v1 = *(const float4*)(hb + s1 + ch4);
                acc.x = silu_acc(v0.x, hdv.x, acc.x);
                acc.y = silu_acc(v0.y, hdv.y, acc.y);
                acc.z = silu_acc(v0.z, hdv.z, acc.z);
                acc.w = silu_acc(v0.w, hdv.w, acc.w);
                acc.x = silu_acc(v1.x, hdv.x, acc.x);
                acc.y = silu_acc(v1.y, hdv.y, acc.y);
                acc.z = silu_acc(v1.z, hdv.z, acc.z);
                acc.w = silu_acc(v1.w, hdv.w, acc.w);
            }
            if (i < end) {
                int s0 = ssrc[i] << 8;
                float4 v0 = *(const float4*)(hb + s0 + ch4);
                acc.x = silu_acc(v0.x, hdv.x, acc.x);
                acc.y = silu_acc(v0.y, hdv.y, acc.y);
                acc.z = silu_acc(v0.z, hdv.z, acc.z);
                acc.w = silu_acc(v0.w, hdv.w, acc.w);
            }
            acc.x += __shfl_xor(acc.x, 16); acc.x += __shfl_xor(acc.x, 32);
            acc.y += __shfl_xor(acc.y, 16); acc.y += __shfl_xor(acc.y, 32);
            acc.z += __shfl_xor(acc.z, 16); acc.z += __shfl_xor(acc.z, 32);
            acc.w += __shfl_xor(acc.w, 16); acc.w += __shfl_xor(acc.w, 32);
            if (eg == 0) *(float4*)(&TG[j * 68 + chb]) = acc;
        }
    }
    // TG is wave-private: no __syncthreads needed.

    // ---- update phase ----
    float hf[16];
    *(float4*)&hf[0]  = *(const float4*)(h + (size_t)hrow * DH + k0);
    *(float4*)&hf[4]  = *(const float4*)(h + (size_t)hrow * DH + k0 + 4);
    *(float4*)&hf[8]  = *(const float4*)(h + (size_t)hrow * DH + 32 + k0);
    *(float4*)&hf[12] = *(const float4*)(h + (size_t)hrow * DH + 32 + k0 + 4);
    Frag ha0 = split8(&hf[0]), ha1 = split8(&hf[8]);

    float gf[16];
    #pragma unroll
    for (int i = 0; i < 8; ++i) gf[i] = TG[arow * 68 + k0 + i];
    #pragma unroll
    for (int i = 0; i < 8; ++i) gf[8 + i] = TG[arow * 68 + 32 + k0 + i];
    Frag ga0 = split8(&gf[0]), ga1 = split8(&gf[8]);

    // stage 1: agg = aggpre @ W2 + deg * b2
    const uint4* PW2H = pack + (size_t)(l * 6 + 2) * 8 * 64;
    const uint4* PW2L = PW2H + LOB;
    float degv[4];
    #pragma unroll
    for (int r = 0; r < 4; ++r)
        degv[r] = (float)counts[(rowbase + kgrp * 4 + r) & (NN - 1)];
    #pragma unroll
    for (int nt = 0; nt < 4; ++nt) {
        float b2v = b2[nt * 16 + (lane & 15)];
        f32x4 a;
        #pragma unroll
        for (int r = 0; r < 4; ++r) a[r] = degv[r] * b2v;
        a = mm3(ga0, PW2H[(nt * 2 + 0) * 64 + lane], PW2L[(nt * 2 + 0) * 64 + lane], a);
        a = mm3(ga1, PW2H[(nt * 2 + 1) * 64 + lane], PW2L[(nt * 2 + 1) * 64 + lane], a);
        #pragma unroll
        for (int r = 0; r < 4; ++r)
            TA[(kgrp * 4 + r) * 68 + nt * 16 + (lane & 15)] = a[r];
    }
    float za[16];
    #pragma unroll
    for (int i = 0; i < 8; ++i) za[i] = TA[arow * 68 + k0 + i];
    #pragma unroll
    for (int i = 0; i < 8; ++i) za[8 + i] = TA[arow * 68 + 32 + k0 + i];
    Frag ka0 = split8(&za[0]), ka1 = split8(&za[8]);

    // stage 2: z = silu([h, agg] @ U1 + ub1)
    const uint4* PU1tH = pack + (size_t)(l * 6 + 3) * 8 * 64;
    const uint4* PU1bH = pack + (size_t)(l * 6 + 4) * 8 * 64;
    const uint4* PU1tL = PU1tH + LOB;
    const uint4* PU1bL = PU1bH + LOB;
    #pragma unroll
    for (int nt = 0; nt < 4; ++nt) {
        float bv = ub1[nt * 16 + (lane & 15)];
        f32x4 a;
        #pragma unroll
        for (int r = 0; r < 4; ++r) a[r] = bv;
        a = mm3(ha0, PU1tH[(nt * 2 + 0) * 64 + lane], PU1tL[(nt * 2 + 0) * 64 + lane], a);
        a = mm3(ha1, PU1tH[(nt * 2 + 1) * 64 + lane], PU1tL[(nt * 2 + 1) * 64 + lane], a);
        a = mm3(ka0, PU1bH[(nt * 2 + 0) * 64 + lane], PU1bL[(nt * 2 + 0) * 64 + lane], a);
        a = mm3(ka1, PU1bH[(nt * 2 + 1) * 64 + lane], PU1bL[(nt * 2 + 1) * 64 + lane], a);
        #pragma unroll
        for (int r = 0; r < 4; ++r)
            TB[(kgrp * 4 + r) * 68 + nt * 16 + (lane & 15)] = silu_f(a[r]);
    }
    float zb[16];
    #pragma unroll
    for (int i = 0; i < 8; ++i) zb[i] = TB[arow * 68 + k0 + i];
    #pragma unroll
    for (int i = 0; i < 8; ++i) zb[8 + i] = TB[arow * 68 + 32 + k0 + i];
    Frag kz0 = split8(&zb[0]), kz1 = split8(&zb[8]);

    // stage 3: hnew = h + z @ U2 + ub2
    const uint4* PU2H = pack + (size_t)(l * 6 + 5) * 8 * 64;
    const uint4* PU2L = PU2H + LOB;
    #pragma unroll
    for (int nt = 0; nt < 4; ++nt) {
        float bv = ub2[nt * 16 + (lane & 15)];
        f32x4 a;
        #pragma unroll
        for (int r = 0; r < 4; ++r) a[r] = bv;
        a = mm3(kz0, PU2H[(nt * 2 + 0) * 64 + lane], PU2L[(nt * 2 + 0) * 64 + lane], a);
        a = mm3(kz1, PU2H[(nt * 2 + 1) * 64 + lane], PU2L[(nt * 2 + 1) * 64 + lane], a);
        #pragma unroll
        for (int r = 0; r < 4; ++r)
            TA[(kgrp * 4 + r) * 68 + nt * 16 + (lane & 15)] = a[r];
    }
    float hn[16];
    #pragma unroll
    for (int i = 0; i < 8; ++i) hn[i] = hf[i] + TA[arow * 68 + k0 + i];
    #pragma unroll
    for (int i = 0; i < 8; ++i) hn[8 + i] = hf[8 + i] + TA[arow * 68 + 32 + k0 + i];

    if (last) {
        float v = 0.f;
        #pragma unroll
        for (int i = 0; i < 8; ++i) v += hn[i] * ro_w[k0 + i];
        #pragma unroll
        for (int i = 0; i < 8; ++i) v += hn[8 + i] * ro_w[32 + k0 + i];
        v += __shfl_xor(v, 16);
        v += __shfl_xor(v, 32);
        if (lane < 16) out[rowbase + lane] = v + ro_b[0];
        return;
    }

    *(float4*)(h + (size_t)hrow * DH + k0) = make_float4(hn[0], hn[1], hn[2], hn[3]);
    *(float4*)(h + (size_t)hrow * DH + k0 + 4) = make_float4(hn[4], hn[5], hn[6], hn[7]);
    *(float4*)(h + (size_t)hrow * DH + 32 + k0) = make_float4(hn[8], hn[9], hn[10], hn[11]);
    *(float4*)(h + (size_t)hrow * DH + 32 + k0 + 4) = make_float4(hn[12], hn[13], hn[14], hn[15]);

    Frag na0 = split8(&hn[0]), na1 = split8(&hn[8]);
    const uint4* PWtH = pack + (size_t)((l + 1) * 6 + 0) * 8 * 64;
    const uint4* PWbH = pack + (size_t)((l + 1) * 6 + 1) * 8 * 64;
    const uint4* PWtL = PWtH + LOB;
    const uint4* PWbL = PWbH + LOB;
    #pragma unroll
    for (int nt = 0; nt < 4; ++nt) {
        f32x4 s; f32x4 d;
        float b1v = b1n[nt * 16 + (lane & 15)];
        #pragma unroll
        for (int r = 0; r < 4; ++r) { s[r] = 0.f; d[r] = b1v; }
        s = mm3(na0, PWtH[(nt * 2 + 0) * 64 + lane], PWtL[(nt * 2 + 0) * 64 + lane], s);
        s = mm3(na1, PWtH[(nt * 2 + 1) * 64 + lane], PWtL[(nt * 2 + 1) * 64 + lane], s);
        d = mm3(na0, PWbH[(nt * 2 + 0) * 64 + lane], PWbL[(nt * 2 + 0) * 64 + lane], d);
        d = mm3(na1, PWbH[(nt * 2 + 1) * 64 + lane], PWbL[(nt * 2 + 1) * 64 + lane], d);
        #pragma unroll
        for (int r = 0; r < 4; ++r) {
            int rr = rowbase + kgrp * 4 + r;
            hs_out[(size_t)rr * DH + nt * 16 + (lane & 15)] = s[r];
            hd[(size_t)rr * DH + nt * 16 + (lane & 15)] = d[r];
        }
    }
}

extern "C" void kernel_launch(void* const* d_in, const int* in_sizes, int n_in,
                              void* d_out, int out_size, void* d_ws, size_t ws_size,
                              hipStream_t stream) {
    const float* t      = (const float*)d_in[0];
    const int*   ei     = (const int*)d_in[1];
    const float* enc_w  = (const float*)d_in[2];
    const float* enc_b  = (const float*)d_in[3];
    const float* msg1_w = (const float*)d_in[4];
    const float* msg1_b = (const float*)d_in[5];
    const float* msg2_w = (const float*)d_in[6];
    const float* msg2_b = (const float*)d_in[7];
    const float* upd1_w = (const float*)d_in[8];
    const float* upd1_b = (const float*)d_in[9];
    const float* upd2_w = (const float*)d_in[10];
    const float* upd2_b = (const float*)d_in[11];
    const float* ro_w   = (const float*)d_in[12];
    const float* ro_b   = (const float*)d_in[13];
    float* out = (float*)d_out;

    const size_t HN = (size_t)TT * NN * DH;   // 4 Mi elements
    float* h    = (float*)d_ws;                     // 16 MB
    float* hs0  = h + HN;                           // 16 MB
    float* hs1  = hs0 + HN;                         // 16 MB
    float* hd   = hs1 + HN;                         // 16 MB
    uint4* pack = (uint4*)(hd + HN);                // 288 KB (hi+lo)
    int* counts  = (int*)(pack + 2 * LOB);
    int* offsets = counts + NN;
    int* ssrc    = offsets + NN + 1;

    setup_kernel<<<19, 512, 0, stream>>>(ei, msg1_w, msg2_w, upd1_w, upd2_w,
                                         pack, counts, offsets, ssrc);

    encode_mfma_kernel<<<TT * NN / 64, 256, 0, stream>>>(
        t, enc_w, enc_b, msg1_b, pack, h, hs0, hd);

    float* hsbuf[2] = {hs0, hs1};
    for (int l = 0; l < 3; ++l) {
        int last = (l == 2);
        layer_kernel<<<TT * NN / 64, 256, 0, stream>>>(
            h, hsbuf[l & 1], hsbuf[(l + 1) & 1], hd,
            counts, offsets, ssrc, pack, l,
            msg2_b + (size_t)l * DH, upd1_b + (size_t)l * DH,
            upd2_b + (size_t)l * DH,
            last ? msg1_b : msg1_b + (size_t)(l + 1) * DH,
            ro_w, ro_b, out, last);
    }
}

// Round 8
// 275.482 us; speedup vs baseline: 1.2693x; 1.2693x over previous
//
#include <hip/hip_runtime.h>

#define TT 128
#define NN 512
#define DH 64
#define EE 8192
#define LOB (18 * 8 * 64)   // uint4 count of hi-weight fragments

typedef __bf16 bf16x8 __attribute__((ext_vector_type(8)));
typedef float f32x4 __attribute__((ext_vector_type(4)));

struct US8 { unsigned short u[8]; };
struct Frag { bf16x8 hi, lo; };

static __device__ __forceinline__ unsigned short f2bf(float x) {
    union { float f; unsigned u; } c; c.f = x;
    unsigned r = (c.u + 0x7FFFu + ((c.u >> 16) & 1u)) >> 16;   // RNE
    return (unsigned short)r;
}
static __device__ __forceinline__ float bf2f(unsigned short b) {
    union { unsigned u; float f; } c; c.u = ((unsigned)b) << 16;
    return c.f;
}
// fast silu accumulate: acc + x * rcp(1 + exp(-x))
static __device__ __forceinline__ float silu_acc(float a, float b, float acc) {
    float x = a + b;
    float e = __expf(-x);
    return fmaf(x, __builtin_amdgcn_rcpf(1.0f + e), acc);
}
static __device__ __forceinline__ float silu_f(float x) {
    float e = __expf(-x);
    return x * __builtin_amdgcn_rcpf(1.0f + e);
}
// split fp32 -> hi/lo bf16 via native casts (v_cvt_pk_bf16_f32)
static __device__ __forceinline__ Frag split8(const float* v) {
    Frag f;
    #pragma unroll
    for (int i = 0; i < 8; ++i) {
        __bf16 hb = (__bf16)v[i];
        f.hi[i] = hb;
        f.lo[i] = (__bf16)(v[i] - (float)hb);
    }
    return f;
}
static __device__ __forceinline__ f32x4 mmac(bf16x8 a, uint4 bw, f32x4 c) {
    return __builtin_amdgcn_mfma_f32_16x16x32_bf16(
        a, __builtin_bit_cast(bf16x8, bw), c, 0, 0, 0);
}
static __device__ __forceinline__ f32x4 mm3(Frag a, uint4 wh, uint4 wl, f32x4 c) {
    c = mmac(a.hi, wh, c);
    c = mmac(a.lo, wh, c);
    c = mmac(a.hi, wl, c);
    return c;
}

// ---- fused setup: blocks 0-17 prepack weights; block 18 builds CSR ----
__global__ __launch_bounds__(512) void setup_kernel(
    const int* __restrict__ ei,
    const float* __restrict__ msg1_w, const float* __restrict__ msg2_w,
    const float* __restrict__ upd1_w, const float* __restrict__ upd2_w,
    uint4* __restrict__ pack,
    int* __restrict__ counts, int* __restrict__ offsets,
    int* __restrict__ ssrc) {
    int b = blockIdx.x;
    if (b < 18) {
        int l = b / 6, bi = b % 6;
        const float* W;
        if (bi == 0)      W = msg1_w + (size_t)l * 128 * 64;
        else if (bi == 1) W = msg1_w + (size_t)l * 128 * 64 + 64 * 64;
        else if (bi == 2) W = msg2_w + (size_t)l * 64 * 64;
        else if (bi == 3) W = upd1_w + (size_t)l * 128 * 64;
        else if (bi == 4) W = upd1_w + (size_t)l * 128 * 64 + 64 * 64;
        else              W = upd2_w + (size_t)l * 64 * 64;
        int lane = threadIdx.x & 63;
        int sub  = threadIdx.x >> 6;          // 0..7 = nt*2+kc
        int nt = sub >> 1, kc = sub & 1;
        US8 oh, ol;
        #pragma unroll
        for (int i = 0; i < 8; ++i) {
            int k = kc * 32 + (lane >> 4) * 8 + i;
            int col = nt * 16 + (lane & 15);
            float w = W[k * 64 + col];
            unsigned short hu = f2bf(w);
            oh.u[i] = hu;
            ol.u[i] = f2bf(w - bf2f(hu));
        }
        size_t fi = ((size_t)b * 8 + sub) * 64 + lane;
        pack[fi]       = __builtin_bit_cast(uint4, oh);
        pack[LOB + fi] = __builtin_bit_cast(uint4, ol);
        return;
    }
    // CSR build in one block, all in LDS
    __shared__ int cnt[NN];
    __shared__ int tmp[NN];
    __shared__ int cur[NN];
    int i = threadIdx.x;
    cnt[i] = 0;
    __syncthreads();
    #pragma unroll
    for (int r = 0; r < EE / 512; ++r)
        atomicAdd(&cnt[ei[EE + r * 512 + i]], 1);
    __syncthreads();
    int c = cnt[i];
    tmp[i] = c;
    __syncthreads();
    for (int off = 1; off < NN; off <<= 1) {
        int v = (i >= off) ? tmp[i - off] : 0;
        __syncthreads();
        tmp[i] += v;
        __syncthreads();
    }
    counts[i] = c;
    offsets[i + 1] = tmp[i];
    if (i == 0) offsets[0] = 0;
    cur[i] = tmp[i] - c;
    __syncthreads();
    #pragma unroll
    for (int r = 0; r < EE / 512; ++r) {
        int e = r * 512 + i;
        int dst = ei[EE + e];
        int pos = atomicAdd(&cur[dst], 1);
        ssrc[pos] = ei[e];
    }
}

// XCD-affine mapping for 1024-block row kernels (encode/upd):
// all 8 blocks of a tt on one XCD; same tt->XCD map in every kernel.
static __device__ __forceinline__ int swz_rowbase(int bid, int w) {
    int xcd = bid & 7;
    int idx = bid >> 3;                 // 0..127
    int tt  = xcd * 16 + (idx >> 3);    // 16 tt per XCD
    int sub = idx & 7;                  // 64-row chunk within tt
    return tt * NN + sub * 64 + w * 16;
}

// ---- encode + layer-0 projections (split MFMA). Wave = 16 rows. ----
__global__ __launch_bounds__(256) void encode_mfma_kernel(
    const float* __restrict__ t, const float* __restrict__ enc_w,
    const float* __restrict__ enc_b, const float* __restrict__ b1,
    const uint4* __restrict__ pack,
    float* __restrict__ h, float* __restrict__ hs, float* __restrict__ hd) {
    int lane = threadIdx.x & 63;
    int rowbase = swz_rowbase(blockIdx.x, threadIdx.x >> 6);
    int arow = lane & 15, kgrp = lane >> 4, k0 = kgrp * 8;
    int row = rowbase + arow;
    int tt = row >> 9, n = row & (NN - 1);
    float tv = t[tt];

    float hv[16];
    #pragma unroll
    for (int kc = 0; kc < 2; ++kc) {
        #pragma unroll
        for (int i = 0; i < 8; ++i) {
            int k = kc * 32 + k0 + i;
            hv[kc * 8 + i] = tv * enc_w[k] + enc_w[(1 + n) * DH + k] + enc_b[k];
        }
        *(float4*)(h + (size_t)row * DH + kc * 32 + k0) =
            make_float4(hv[kc * 8], hv[kc * 8 + 1], hv[kc * 8 + 2], hv[kc * 8 + 3]);
        *(float4*)(h + (size_t)row * DH + kc * 32 + k0 + 4) =
            make_float4(hv[kc * 8 + 4], hv[kc * 8 + 5], hv[kc * 8 + 6], hv[kc * 8 + 7]);
    }
    Frag a0 = split8(&hv[0]), a1 = split8(&hv[8]);

    const uint4* PWtH = pack;
    const uint4* PWbH = pack + 8 * 64;
    const uint4* PWtL = PWtH + LOB;
    const uint4* PWbL = PWbH + LOB;
    #pragma unroll
    for (int nt = 0; nt < 4; ++nt) {
        f32x4 s; f32x4 d;
        float b1v = b1[nt * 16 + (lane & 15)];
        #pragma unroll
        for (int r = 0; r < 4; ++r) { s[r] = 0.f; d[r] = b1v; }
        s = mm3(a0, PWtH[(nt * 2 + 0) * 64 + lane], PWtL[(nt * 2 + 0) * 64 + lane], s);
        s = mm3(a1, PWtH[(nt * 2 + 1) * 64 + lane], PWtL[(nt * 2 + 1) * 64 + lane], s);
        d = mm3(a0, PWbH[(nt * 2 + 0) * 64 + lane], PWbL[(nt * 2 + 0) * 64 + lane], d);
        d = mm3(a1, PWbH[(nt * 2 + 1) * 64 + lane], PWbL[(nt * 2 + 1) * 64 + lane], d);
        #pragma unroll
        for (int r = 0; r < 4; ++r) {
            int rr = rowbase + kgrp * 4 + r;
            hs[(size_t)rr * DH + nt * 16 + (lane & 15)] = s[r];
            hd[(size_t)rr * DH + nt * 16 + (lane & 15)] = d[r];
        }
    }
}

// ---- edge aggregation: one wave per (tt,n); 8 edges in flight ----
// XCD-affine: 128 consecutive-id blocks (one whole tt) per XCD.
__global__ __launch_bounds__(256) void agg_kernel(
    const float* __restrict__ hs, const float* __restrict__ hd,
    const int* __restrict__ offsets, const int* __restrict__ ssrc,
    float* __restrict__ aggpre) {
    int bid = blockIdx.x;
    int xcd = bid & 7;
    int idx = bid >> 3;                       // 0..2047
    int tt  = xcd * 16 + (idx >> 7);          // 16 tt per XCD
    int n   = (idx & 127) * 4 + (threadIdx.x >> 6);
    int lane = threadIdx.x & 63;
    size_t rowoff = ((size_t)tt * NN + n) * DH;
    int eg = lane >> 4;                 // edge slot 0..3
    int ch4 = (lane & 15) * 16;         // byte offset of this lane's float4
    float4 hdv = *(const float4*)(hd + rowoff + (lane & 15) * 4);
    int beg = offsets[n], end = offsets[n + 1];
    const char* hb = (const char*)(hs + (size_t)tt * NN * DH);
    float4 acc = make_float4(0.f, 0.f, 0.f, 0.f);
    int i = beg + eg;
    for (; i + 4 < end; i += 8) {
        int s0 = ssrc[i] << 8;
        int s1 = ssrc[i + 4] << 8;
        float4 v0 = *(const float4*)(hb + s0 + ch4);
        float4 v1 = *(const float4*)(hb + s1 + ch4);
        acc.x = silu_acc(v0.x, hdv.x, acc.x);
        acc.y = silu_acc(v0.y, hdv.y, acc.y);
        acc.z = silu_acc(v0.z, hdv.z, acc.z);
        acc.w = silu_acc(v0.w, hdv.w, acc.w);
        acc.x = silu_acc(v1.x, hdv.x, acc.x);
        acc.y = silu_acc(v1.y, hdv.y, acc.y);
        acc.z = silu_acc(v1.z, hdv.z, acc.z);
        acc.w = silu_acc(v1.w, hdv.w, acc.w);
    }
    if (i < end) {
        int s0 = ssrc[i] << 8;
        float4 v0 = *(const float4*)(hb + s0 + ch4);
        acc.x = silu_acc(v0.x, hdv.x, acc.x);
        acc.y = silu_acc(v0.y, hdv.y, acc.y);
        acc.z = silu_acc(v0.z, hdv.z, acc.z);
        acc.w = silu_acc(v0.w, hdv.w, acc.w);
    }
    acc.x += __shfl_xor(acc.x, 16); acc.x += __shfl_xor(acc.x, 32);
    acc.y += __shfl_xor(acc.y, 16); acc.y += __shfl_xor(acc.y, 32);
    acc.z += __shfl_xor(acc.z, 16); acc.z += __shfl_xor(acc.z, 32);
    acc.w += __shfl_xor(acc.w, 16); acc.w += __shfl_xor(acc.w, 32);
    if (eg == 0) *(float4*)(aggpre + rowoff + (lane & 15) * 4) = acc;
}

// ---- fused update MLP + (next-layer projections | readout), split MFMA ----
// Single reusable LDS tile per wave (17 KB/block -> 2x occupancy headroom).
__global__ __launch_bounds__(256) void upd_mfma_kernel(
    float* __restrict__ h, const float* __restrict__ aggpre,
    const int* __restrict__ counts, const uint4* __restrict__ pack, int l,
    const float* __restrict__ b2, const float* __restrict__ ub1,
    const float* __restrict__ ub2, const float* __restrict__ b1n,
    float* __restrict__ hs, float* __restrict__ hd,
    const float* __restrict__ ro_w, const float* __restrict__ ro_b,
    float* __restrict__ out, int last) {
    __shared__ float tile[4][16 * 68];
    int lane = threadIdx.x & 63;
    int w = threadIdx.x >> 6;
    int rowbase = swz_rowbase(blockIdx.x, w);
    float* TA = tile[w];
    int arow = lane & 15, kgrp = lane >> 4, k0 = kgrp * 8;
    int hrow = rowbase + arow;

    float hf[16];
    *(float4*)&hf[0]  = *(const float4*)(h + (size_t)hrow * DH + k0);
    *(float4*)&hf[4]  = *(const float4*)(h + (size_t)hrow * DH + k0 + 4);
    *(float4*)&hf[8]  = *(const float4*)(h + (size_t)hrow * DH + 32 + k0);
    *(float4*)&hf[12] = *(const float4*)(h + (size_t)hrow * DH + 32 + k0 + 4);
    Frag ha0 = split8(&hf[0]), ha1 = split8(&hf[8]);

    float gf[16];
    *(float4*)&gf[0]  = *(const float4*)(aggpre + (size_t)hrow * DH + k0);
    *(float4*)&gf[4]  = *(const float4*)(aggpre + (size_t)hrow * DH + k0 + 4);
    *(float4*)&gf[8]  = *(const float4*)(aggpre + (size_t)hrow * DH + 32 + k0);
    *(float4*)&gf[12] = *(const float4*)(aggpre + (size_t)hrow * DH + 32 + k0 + 4);
    Frag ga0 = split8(&gf[0]), ga1 = split8(&gf[8]);

    // stage 1: agg = aggpre @ W2 + deg * b2
    const uint4* PW2H = pack + (size_t)(l * 6 + 2) * 8 * 64;
    const uint4* PW2L = PW2H + LOB;
    float degv[4];
    #pragma unroll
    for (int r = 0; r < 4; ++r)
        degv[r] = (float)counts[(rowbase + kgrp * 4 + r) & (NN - 1)];
    #pragma unroll
    for (int nt = 0; nt < 4; ++nt) {
        float b2v = b2[nt * 16 + (lane & 15)];
        f32x4 a;
        #pragma unroll
        for (int r = 0; r < 4; ++r) a[r] = degv[r] * b2v;
        a = mm3(ga0, PW2H[(nt * 2 + 0) * 64 + lane], PW2L[(nt * 2 + 0) * 64 + lane], a);
        a = mm3(ga1, PW2H[(nt * 2 + 1) * 64 + lane], PW2L[(nt * 2 + 1) * 64 + lane], a);
        #pragma unroll
        for (int r = 0; r < 4; ++r)
            TA[(kgrp * 4 + r) * 68 + nt * 16 + (lane & 15)] = a[r];
    }
    float za[16];
    #pragma unroll
    for (int i = 0; i < 8; ++i) za[i] = TA[arow * 68 + k0 + i];
    #pragma unroll
    for (int i = 0; i < 8; ++i) za[8 + i] = TA[arow * 68 + 32 + k0 + i];
    Frag ka0 = split8(&za[0]), ka1 = split8(&za[8]);

    // stage 2: z = silu([h, agg] @ U1 + ub1)
    const uint4* PU1tH = pack + (size_t)(l * 6 + 3) * 8 * 64;
    const uint4* PU1bH = pack + (size_t)(l * 6 + 4) * 8 * 64;
    const uint4* PU1tL = PU1tH + LOB;
    const uint4* PU1bL = PU1bH + LOB;
    #pragma unroll
    for (int nt = 0; nt < 4; ++nt) {
        float bv = ub1[nt * 16 + (lane & 15)];
        f32x4 a;
        #pragma unroll
        for (int r = 0; r < 4; ++r) a[r] = bv;
        a = mm3(ha0, PU1tH[(nt * 2 + 0) * 64 + lane], PU1tL[(nt * 2 + 0) * 64 + lane], a);
        a = mm3(ha1, PU1tH[(nt * 2 + 1) * 64 + lane], PU1tL[(nt * 2 + 1) * 64 + lane], a);
        a = mm3(ka0, PU1bH[(nt * 2 + 0) * 64 + lane], PU1bL[(nt * 2 + 0) * 64 + lane], a);
        a = mm3(ka1, PU1bH[(nt * 2 + 1) * 64 + lane], PU1bL[(nt * 2 + 1) * 64 + lane], a);
        #pragma unroll
        for (int r = 0; r < 4; ++r)
            TA[(kgrp * 4 + r) * 68 + nt * 16 + (lane & 15)] = silu_f(a[r]);
    }
    float zb[16];
    #pragma unroll
    for (int i = 0; i < 8; ++i) zb[i] = TA[arow * 68 + k0 + i];
    #pragma unroll
    for (int i = 0; i < 8; ++i) zb[8 + i] = TA[arow * 68 + 32 + k0 + i];
    Frag kz0 = split8(&zb[0]), kz1 = split8(&zb[8]);

    // stage 3: hnew = h + z @ U2 + ub2
    const uint4* PU2H = pack + (size_t)(l * 6 + 5) * 8 * 64;
    const uint4* PU2L = PU2H + LOB;
    #pragma unroll
    for (int nt = 0; nt < 4; ++nt) {
        float bv = ub2[nt * 16 + (lane & 15)];
        f32x4 a;
        #pragma unroll
        for (int r = 0; r < 4; ++r) a[r] = bv;
        a = mm3(kz0, PU2H[(nt * 2 + 0) * 64 + lane], PU2L[(nt * 2 + 0) * 64 + lane], a);
        a = mm3(kz1, PU2H[(nt * 2 + 1) * 64 + lane], PU2L[(nt * 2 + 1) * 64 + lane], a);
        #pragma unroll
        for (int r = 0; r < 4; ++r)
            TA[(kgrp * 4 + r) * 68 + nt * 16 + (lane & 15)] = a[r];
    }
    float hn[16];
    #pragma unroll
    for (int i = 0; i < 8; ++i) hn[i] = hf[i] + TA[arow * 68 + k0 + i];
    #pragma unroll
    for (int i = 0; i < 8; ++i) hn[8 + i] = hf[8 + i] + TA[arow * 68 + 32 + k0 + i];

    if (last) {
        float v = 0.f;
        #pragma unroll
        for (int i = 0; i < 8; ++i) v += hn[i] * ro_w[k0 + i];
        #pragma unroll
        for (int i = 0; i < 8; ++i) v += hn[8 + i] * ro_w[32 + k0 + i];
        v += __shfl_xor(v, 16);
        v += __shfl_xor(v, 32);
        if (lane < 16) out[rowbase + lane] = v + ro_b[0];
        return;
    }

    *(float4*)(h + (size_t)hrow * DH + k0) = make_float4(hn[0], hn[1], hn[2], hn[3]);
    *(float4*)(h + (size_t)hrow * DH + k0 + 4) = make_float4(hn[4], hn[5], hn[6], hn[7]);
    *(float4*)(h + (size_t)hrow * DH + 32 + k0) = make_float4(hn[8], hn[9], hn[10], hn[11]);
    *(float4*)(h + (size_t)hrow * DH + 32 + k0 + 4) = make_float4(hn[12], hn[13], hn[14], hn[15]);

    Frag na0 = split8(&hn[0]), na1 = split8(&hn[8]);
    const uint4* PWtH = pack + (size_t)((l + 1) * 6 + 0) * 8 * 64;
    const uint4* PWbH = pack + (size_t)((l + 1) * 6 + 1) * 8 * 64;
    const uint4* PWtL = PWtH + LOB;
    const uint4* PWbL = PWbH + LOB;
    #pragma unroll
    for (int nt = 0; nt < 4; ++nt) {
        f32x4 s; f32x4 d;
        float b1v = b1n[nt * 16 + (lane & 15)];
        #pragma unroll
        for (int r = 0; r < 4; ++r) { s[r] = 0.f; d[r] = b1v; }
        s = mm3(na0, PWtH[(nt * 2 + 0) * 64 + lane], PWtL[(nt * 2 + 0) * 64 + lane], s);
        s = mm3(na1, PWtH[(nt * 2 + 1) * 64 + lane], PWtL[(nt * 2 + 1) * 64 + lane], s);
        d = mm3(na0, PWbH[(nt * 2 + 0) * 64 + lane], PWbL[(nt * 2 + 0) * 64 + lane], d);
        d = mm3(na1, PWbH[(nt * 2 + 1) * 64 + lane], PWbL[(nt * 2 + 1) * 64 + lane], d);
        #pragma unroll
        for (int r = 0; r < 4; ++r) {
            int rr = rowbase + kgrp * 4 + r;
            hs[(size_t)rr * DH + nt * 16 + (lane & 15)] = s[r];
            hd[(size_t)rr * DH + nt * 16 + (lane & 15)] = d[r];
        }
    }
}

extern "C" void kernel_launch(void* const* d_in, const int* in_sizes, int n_in,
                              void* d_out, int out_size, void* d_ws, size_t ws_size,
                              hipStream_t stream) {
    const float* t      = (const float*)d_in[0];
    const int*   ei     = (const int*)d_in[1];
    const float* enc_w  = (const float*)d_in[2];
    const float* enc_b  = (const float*)d_in[3];
    const float* msg1_w = (const float*)d_in[4];
    const float* msg1_b = (const float*)d_in[5];
    const float* msg2_w = (const float*)d_in[6];
    const float* msg2_b = (const float*)d_in[7];
    const float* upd1_w = (const float*)d_in[8];
    const float* upd1_b = (const float*)d_in[9];
    const float* upd2_w = (const float*)d_in[10];
    const float* upd2_b = (const float*)d_in[11];
    const float* ro_w   = (const float*)d_in[12];
    const float* ro_b   = (const float*)d_in[13];
    float* out = (float*)d_out;

    const size_t HN = (size_t)TT * NN * DH;   // 4 Mi elements
    float* h      = (float*)d_ws;                   // 16 MB
    float* hs     = h + HN;                         // 16 MB
    float* hd     = hs + HN;                        // 16 MB
    float* aggpre = hd + HN;                        // 16 MB
    uint4* pack   = (uint4*)(aggpre + HN);          // 288 KB (hi+lo)
    int* counts  = (int*)(pack + 2 * LOB);
    int* offsets = counts + NN;
    int* ssrc    = offsets + NN + 1;

    setup_kernel<<<19, 512, 0, stream>>>(ei, msg1_w, msg2_w, upd1_w, upd2_w,
                                         pack, counts, offsets, ssrc);

    encode_mfma_kernel<<<TT * NN / 64, 256, 0, stream>>>(
        t, enc_w, enc_b, msg1_b, pack, h, hs, hd);

    for (int l = 0; l < 3; ++l) {
        agg_kernel<<<TT * NN / 4, 256, 0, stream>>>(
            hs, hd, offsets, ssrc, aggpre);
        int last = (l == 2);
        upd_mfma_kernel<<<TT * NN / 64, 256, 0, stream>>>(
            h, aggpre, counts, pack, l,
            msg2_b + (size_t)l * DH, upd1_b + (size_t)l * DH,
            upd2_b + (size_t)l * DH,
            last ? msg1_b : msg1_b + (size_t)(l + 1) * DH,
            hs, hd, ro_w, ro_b, out, last);
    }
}

// Round 10
// 247.059 us; speedup vs baseline: 1.4154x; 1.1150x over previous
//
#include <hip/hip_runtime.h>

#define TT 128
#define NN 512
#define DH 64
#define EE 8192
#define LOB (18 * 8 * 64)   // uint4 count of hi-weight fragments

typedef __bf16 bf16x8 __attribute__((ext_vector_type(8)));
typedef float f32x4 __attribute__((ext_vector_type(4)));

struct US8 { unsigned short u[8]; };
struct Frag { bf16x8 hi, lo; };

static __device__ __forceinline__ unsigned short f2bf(float x) {
    union { float f; unsigned u; } c; c.f = x;
    unsigned r = (c.u + 0x7FFFu + ((c.u >> 16) & 1u)) >> 16;   // RNE
    return (unsigned short)r;
}
static __device__ __forceinline__ float bf2f(unsigned short b) {
    union { unsigned u; float f; } c; c.u = ((unsigned)b) << 16;
    return c.f;
}
static __device__ __forceinline__ float silu_acc(float a, float b, float acc) {
    float x = a + b;
    float e = __expf(-x);
    return fmaf(x, __builtin_amdgcn_rcpf(1.0f + e), acc);
}
static __device__ __forceinline__ float silu_f(float x) {
    float e = __expf(-x);
    return x * __builtin_amdgcn_rcpf(1.0f + e);
}
static __device__ __forceinline__ Frag split8(const float* v) {
    Frag f;
    #pragma unroll
    for (int i = 0; i < 8; ++i) {
        __bf16 hb = (__bf16)v[i];
        f.hi[i] = hb;
        f.lo[i] = (__bf16)(v[i] - (float)hb);
    }
    return f;
}
static __device__ __forceinline__ f32x4 mmac(bf16x8 a, uint4 bw, f32x4 c) {
    return __builtin_amdgcn_mfma_f32_16x16x32_bf16(
        a, __builtin_bit_cast(bf16x8, bw), c, 0, 0, 0);
}
static __device__ __forceinline__ f32x4 mm3(Frag a, uint4 wh, uint4 wl, f32x4 c) {
    c = mmac(a.hi, wh, c);
    c = mmac(a.lo, wh, c);
    c = mmac(a.hi, wl, c);
    return c;
}

// ---- fused setup ----
// b in [0,17]:  weight prepack (hi/lo bf16 B-fragments)
// b == 18:      CSR build in LDS
// b in [19,82]: E1s/E1d tables: E1s[n]=c_n@W1top(l0), E1d[n]=c_n@W1bot(l0)+b1
// b == 83:      e0sum[d] = (enc_w0 @ (W1top+W1bot))[d]
__global__ __launch_bounds__(512) void setup_kernel(
    const int* __restrict__ ei,
    const float* __restrict__ msg1_w, const float* __restrict__ msg2_w,
    const float* __restrict__ upd1_w, const float* __restrict__ upd2_w,
    const float* __restrict__ enc_w, const float* __restrict__ enc_b,
    const float* __restrict__ msg1_b,
    uint4* __restrict__ pack,
    int* __restrict__ counts, int* __restrict__ offsets,
    int* __restrict__ ssrc,
    float* __restrict__ E1s, float* __restrict__ E1d,
    float* __restrict__ e0sum) {
    int b = blockIdx.x;
    if (b < 18) {
        int l = b / 6, bi = b % 6;
        const float* W;
        if (bi == 0)      W = msg1_w + (size_t)l * 128 * 64;
        else if (bi == 1) W = msg1_w + (size_t)l * 128 * 64 + 64 * 64;
        else if (bi == 2) W = msg2_w + (size_t)l * 64 * 64;
        else if (bi == 3) W = upd1_w + (size_t)l * 128 * 64;
        else if (bi == 4) W = upd1_w + (size_t)l * 128 * 64 + 64 * 64;
        else              W = upd2_w + (size_t)l * 64 * 64;
        int lane = threadIdx.x & 63;
        int sub  = threadIdx.x >> 6;          // 0..7 = nt*2+kc
        int nt = sub >> 1, kc = sub & 1;
        US8 oh, ol;
        #pragma unroll
        for (int i = 0; i < 8; ++i) {
            int k = kc * 32 + (lane >> 4) * 8 + i;
            int col = nt * 16 + (lane & 15);
            float w = W[k * 64 + col];
            unsigned short hu = f2bf(w);
            oh.u[i] = hu;
            ol.u[i] = f2bf(w - bf2f(hu));
        }
        size_t fi = ((size_t)b * 8 + sub) * 64 + lane;
        pack[fi]       = __builtin_bit_cast(uint4, oh);
        pack[LOB + fi] = __builtin_bit_cast(uint4, ol);
        return;
    }
    if (b == 18) {
        // CSR build in one block, all in LDS
        __shared__ int cnt[NN];
        __shared__ int tmp[NN];
        __shared__ int cur[NN];
        int i = threadIdx.x;
        cnt[i] = 0;
        __syncthreads();
        #pragma unroll
        for (int r = 0; r < EE / 512; ++r)
            atomicAdd(&cnt[ei[EE + r * 512 + i]], 1);
        __syncthreads();
        int c = cnt[i];
        tmp[i] = c;
        __syncthreads();
        for (int off = 1; off < NN; off <<= 1) {
            int v = (i >= off) ? tmp[i - off] : 0;
            __syncthreads();
            tmp[i] += v;
            __syncthreads();
        }
        counts[i] = c;
        offsets[i + 1] = tmp[i];
        if (i == 0) offsets[0] = 0;
        cur[i] = tmp[i] - c;
        __syncthreads();
        #pragma unroll
        for (int r = 0; r < EE / 512; ++r) {
            int e = r * 512 + i;
            int dst = ei[EE + e];
            int pos = atomicAdd(&cur[dst], 1);
            ssrc[pos] = ei[e];
        }
        return;
    }
    if (b < 83) {
        // E1s/E1d: 8 rows per block (one per wave), fp32 exact
        int nn = (b - 19) * 8 + (threadIdx.x >> 6);
        int d  = threadIdx.x & 63;
        float s = 0.f, dd = msg1_b[d];
        #pragma unroll 8
        for (int k = 0; k < 64; ++k) {
            float c = enc_w[(1 + nn) * 64 + k] + enc_b[k];
            s  = fmaf(c, msg1_w[k * 64 + d], s);
            dd = fmaf(c, msg1_w[(64 + k) * 64 + d], dd);
        }
        E1s[nn * 64 + d] = s;
        E1d[nn * 64 + d] = dd;
        return;
    }
    // b == 83: e0sum
    if (threadIdx.x < 64) {
        int d = threadIdx.x;
        float s = 0.f, dd = 0.f;
        #pragma unroll 8
        for (int k = 0; k < 64; ++k) {
            float a = enc_w[k];
            s  = fmaf(a, msg1_w[k * 64 + d], s);
            dd = fmaf(a, msg1_w[(64 + k) * 64 + d], dd);
        }
        e0sum[d] = s + dd;
    }
}

// XCD-affine mapping for 1024-block row kernels:
// all 8 blocks of a tt on one XCD; same tt->XCD map in every kernel.
static __device__ __forceinline__ int swz_rowbase(int bid, int w) {
    int xcd = bid & 7;
    int idx = bid >> 3;                 // 0..127
    int tt  = xcd * 16 + (idx >> 3);    // 16 tt per XCD
    int sub = idx & 7;                  // 64-row chunk within tt
    return tt * NN + sub * 64 + w * 16;
}

// ---- layer-0 edge aggregation: gathers from 128KB E1s table (L2-hot) ----
__global__ __launch_bounds__(256) void agg0_kernel(
    const float* __restrict__ t, const float* __restrict__ e0sum,
    const float* __restrict__ E1s, const float* __restrict__ E1d,
    const int* __restrict__ offsets, const int* __restrict__ ssrc,
    float* __restrict__ aggpre) {
    int bid = blockIdx.x;
    int xcd = bid & 7;
    int idx = bid >> 3;                       // 0..2047
    int tt  = xcd * 16 + (idx >> 7);          // 16 tt per XCD
    int n   = (idx & 127) * 4 + (threadIdx.x >> 6);
    int lane = threadIdx.x & 63;
    int eg = lane >> 4;                 // edge slot 0..3
    int chb = (lane & 15) * 4;          // float index of lane's float4
    int ch4 = chb * 4;                  // byte offset
    float tv = t[tt];
    float4 e0 = *(const float4*)(e0sum + chb);
    float4 ed = *(const float4*)(E1d + n * DH + chb);
    float4 base = make_float4(fmaf(tv, e0.x, ed.x), fmaf(tv, e0.y, ed.y),
                              fmaf(tv, e0.z, ed.z), fmaf(tv, e0.w, ed.w));
    int beg = offsets[n], end = offsets[n + 1];
    const char* Eb = (const char*)E1s;
    float4 acc = make_float4(0.f, 0.f, 0.f, 0.f);
    int i = beg + eg;
    for (; i + 4 < end; i += 8) {
        int s0 = ssrc[i] << 8;
        int s1 = ssrc[i + 4] << 8;
        float4 v0 = *(const float4*)(Eb + s0 + ch4);
        float4 v1 = *(const float4*)(Eb + s1 + ch4);
        acc.x = silu_acc(v0.x, base.x, acc.x);
        acc.y = silu_acc(v0.y, base.y, acc.y);
        acc.z = silu_acc(v0.z, base.z, acc.z);
        acc.w = silu_acc(v0.w, base.w, acc.w);
        acc.x = silu_acc(v1.x, base.x, acc.x);
        acc.y = silu_acc(v1.y, base.y, acc.y);
        acc.z = silu_acc(v1.z, base.z, acc.z);
        acc.w = silu_acc(v1.w, base.w, acc.w);
    }
    if (i < end) {
        int s0 = ssrc[i] << 8;
        float4 v0 = *(const float4*)(Eb + s0 + ch4);
        acc.x = silu_acc(v0.x, base.x, acc.x);
        acc.y = silu_acc(v0.y, base.y, acc.y);
        acc.z = silu_acc(v0.z, base.z, acc.z);
        acc.w = silu_acc(v0.w, base.w, acc.w);
    }
    acc.x += __shfl_xor(acc.x, 16); acc.x += __shfl_xor(acc.x, 32);
    acc.y += __shfl_xor(acc.y, 16); acc.y += __shfl_xor(acc.y, 32);
    acc.z += __shfl_xor(acc.z, 16); acc.z += __shfl_xor(acc.z, 32);
    acc.w += __shfl_xor(acc.w, 16); acc.w += __shfl_xor(acc.w, 32);
    if (eg == 0)
        *(float4*)(aggpre + ((size_t)tt * NN + n) * DH + chb) = acc;
}

// ---- layers 1,2 edge aggregation (unchanged from round 8) ----
__global__ __launch_bounds__(256) void agg_kernel(
    const float* __restrict__ hs, const float* __restrict__ hd,
    const int* __restrict__ offsets, const int* __restrict__ ssrc,
    float* __restrict__ aggpre) {
    int bid = blockIdx.x;
    int xcd = bid & 7;
    int idx = bid >> 3;
    int tt  = xcd * 16 + (idx >> 7);
    int n   = (idx & 127) * 4 + (threadIdx.x >> 6);
    int lane = threadIdx.x & 63;
    size_t rowoff = ((size_t)tt * NN + n) * DH;
    int eg = lane >> 4;
    int ch4 = (lane & 15) * 16;
    float4 hdv = *(const float4*)(hd + rowoff + (lane & 15) * 4);
    int beg = offsets[n], end = offsets[n + 1];
    const char* hb = (const char*)(hs + (size_t)tt * NN * DH);
    float4 acc = make_float4(0.f, 0.f, 0.f, 0.f);
    int i = beg + eg;
    for (; i + 4 < end; i += 8) {
        int s0 = ssrc[i] << 8;
        int s1 = ssrc[i + 4] << 8;
        float4 v0 = *(const float4*)(hb + s0 + ch4);
        float4 v1 = *(const float4*)(hb + s1 + ch4);
        acc.x = silu_acc(v0.x, hdv.x, acc.x);
        acc.y = silu_acc(v0.y, hdv.y, acc.y);
        acc.z = silu_acc(v0.z, hdv.z, acc.z);
        acc.w = silu_acc(v0.w, hdv.w, acc.w);
        acc.x = silu_acc(v1.x, hdv.x, acc.x);
        acc.y = silu_acc(v1.y, hdv.y, acc.y);
        acc.z = silu_acc(v1.z, hdv.z, acc.z);
        acc.w = silu_acc(v1.w, hdv.w, acc.w);
    }
    if (i < end) {
        int s0 = ssrc[i] << 8;
        float4 v0 = *(const float4*)(hb + s0 + ch4);
        acc.x = silu_acc(v0.x, hdv.x, acc.x);
        acc.y = silu_acc(v0.y, hdv.y, acc.y);
        acc.z = silu_acc(v0.z, hdv.z, acc.z);
        acc.w = silu_acc(v0.w, hdv.w, acc.w);
    }
    acc.x += __shfl_xor(acc.x, 16); acc.x += __shfl_xor(acc.x, 32);
    acc.y += __shfl_xor(acc.y, 16); acc.y += __shfl_xor(acc.y, 32);
    acc.z += __shfl_xor(acc.z, 16); acc.z += __shfl_xor(acc.z, 32);
    acc.w += __shfl_xor(acc.w, 16); acc.w += __shfl_xor(acc.w, 32);
    if (eg == 0) *(float4*)(aggpre + rowoff + (lane & 15) * 4) = acc;
}

// ---- fused update MLP + (next-layer projections | readout), split MFMA ----
// first=1: h computed inline from enc (layer 0); else loaded from h.
__global__ __launch_bounds__(256) void upd_mfma_kernel(
    float* __restrict__ h, const float* __restrict__ aggpre,
    const float* __restrict__ t, const float* __restrict__ enc_w,
    const float* __restrict__ enc_b,
    const int* __restrict__ counts, const uint4* __restrict__ pack, int l,
    const float* __restrict__ b2, const float* __restrict__ ub1,
    const float* __restrict__ ub2, const float* __restrict__ b1n,
    float* __restrict__ hs, float* __restrict__ hd,
    const float* __restrict__ ro_w, const float* __restrict__ ro_b,
    float* __restrict__ out, int first, int last) {
    __shared__ float tile[4][16 * 68];
    int lane = threadIdx.x & 63;
    int w = threadIdx.x >> 6;
    int rowbase = swz_rowbase(blockIdx.x, w);
    float* TA = tile[w];
    int arow = lane & 15, kgrp = lane >> 4, k0 = kgrp * 8;
    int hrow = rowbase + arow;

    float hf[16];
    if (first) {
        int n = (rowbase & (NN - 1)) + arow;
        float tv = t[rowbase >> 9];
        #pragma unroll
        for (int kc = 0; kc < 2; ++kc)
            #pragma unroll
            for (int i = 0; i < 8; ++i) {
                int k = kc * 32 + k0 + i;
                hf[kc * 8 + i] = tv * enc_w[k] + enc_w[(1 + n) * DH + k] + enc_b[k];
            }
    } else {
        *(float4*)&hf[0]  = *(const float4*)(h + (size_t)hrow * DH + k0);
        *(float4*)&hf[4]  = *(const float4*)(h + (size_t)hrow * DH + k0 + 4);
        *(float4*)&hf[8]  = *(const float4*)(h + (size_t)hrow * DH + 32 + k0);
        *(float4*)&hf[12] = *(const float4*)(h + (size_t)hrow * DH + 32 + k0 + 4);
    }
    Frag ha0 = split8(&hf[0]), ha1 = split8(&hf[8]);

    float gf[16];
    *(float4*)&gf[0]  = *(const float4*)(aggpre + (size_t)hrow * DH + k0);
    *(float4*)&gf[4]  = *(const float4*)(aggpre + (size_t)hrow * DH + k0 + 4);
    *(float4*)&gf[8]  = *(const float4*)(aggpre + (size_t)hrow * DH + 32 + k0);
    *(float4*)&gf[12] = *(const float4*)(aggpre + (size_t)hrow * DH + 32 + k0 + 4);
    Frag ga0 = split8(&gf[0]), ga1 = split8(&gf[8]);

    // stage 1: agg = aggpre @ W2 + deg * b2
    const uint4* PW2H = pack + (size_t)(l * 6 + 2) * 512;
    const uint4* PW2L = PW2H + LOB;
    float degv[4];
    #pragma unroll
    for (int r = 0; r < 4; ++r)
        degv[r] = (float)counts[(rowbase + kgrp * 4 + r) & (NN - 1)];
    #pragma unroll
    for (int nt = 0; nt < 4; ++nt) {
        float b2v = b2[nt * 16 + (lane & 15)];
        f32x4 a;
        #pragma unroll
        for (int r = 0; r < 4; ++r) a[r] = degv[r] * b2v;
        a = mm3(ga0, PW2H[(nt * 2 + 0) * 64 + lane], PW2L[(nt * 2 + 0) * 64 + lane], a);
        a = mm3(ga1, PW2H[(nt * 2 + 1) * 64 + lane], PW2L[(nt * 2 + 1) * 64 + lane], a);
        #pragma unroll
        for (int r = 0; r < 4; ++r)
            TA[(kgrp * 4 + r) * 68 + nt * 16 + (lane & 15)] = a[r];
    }
    float za[16];
    #pragma unroll
    for (int i = 0; i < 8; ++i) za[i] = TA[arow * 68 + k0 + i];
    #pragma unroll
    for (int i = 0; i < 8; ++i) za[8 + i] = TA[arow * 68 + 32 + k0 + i];
    Frag ka0 = split8(&za[0]), ka1 = split8(&za[8]);

    // stage 2: z = silu([h, agg] @ U1 + ub1)
    const uint4* PU1tH = pack + (size_t)(l * 6 + 3) * 512;
    const uint4* PU1bH = pack + (size_t)(l * 6 + 4) * 512;
    const uint4* PU1tL = PU1tH + LOB;
    const uint4* PU1bL = PU1bH + LOB;
    #pragma unroll
    for (int nt = 0; nt < 4; ++nt) {
        float bv = ub1[nt * 16 + (lane & 15)];
        f32x4 a;
        #pragma unroll
        for (int r = 0; r < 4; ++r) a[r] = bv;
        a = mm3(ha0, PU1tH[(nt * 2 + 0) * 64 + lane], PU1tL[(nt * 2 + 0) * 64 + lane], a);
        a = mm3(ha1, PU1tH[(nt * 2 + 1) * 64 + lane], PU1tL[(nt * 2 + 1) * 64 + lane], a);
        a = mm3(ka0, PU1bH[(nt * 2 + 0) * 64 + lane], PU1bL[(nt * 2 + 0) * 64 + lane], a);
        a = mm3(ka1, PU1bH[(nt * 2 + 1) * 64 + lane], PU1bL[(nt * 2 + 1) * 64 + lane], a);
        #pragma unroll
        for (int r = 0; r < 4; ++r)
            TA[(kgrp * 4 + r) * 68 + nt * 16 + (lane & 15)] = silu_f(a[r]);
    }
    float zb[16];
    #pragma unroll
    for (int i = 0; i < 8; ++i) zb[i] = TA[arow * 68 + k0 + i];
    #pragma unroll
    for (int i = 0; i < 8; ++i) zb[8 + i] = TA[arow * 68 + 32 + k0 + i];
    Frag kz0 = split8(&zb[0]), kz1 = split8(&zb[8]);

    // stage 3: hnew = h + z @ U2 + ub2
    const uint4* PU2H = pack + (size_t)(l * 6 + 5) * 512;
    const uint4* PU2L = PU2H + LOB;
    #pragma unroll
    for (int nt = 0; nt < 4; ++nt) {
        float bv = ub2[nt * 16 + (lane & 15)];
        f32x4 a;
        #pragma unroll
        for (int r = 0; r < 4; ++r) a[r] = bv;
        a = mm3(kz0, PU2H[(nt * 2 + 0) * 64 + lane], PU2L[(nt * 2 + 0) * 64 + lane], a);
        a = mm3(kz1, PU2H[(nt * 2 + 1) * 64 + lane], PU2L[(nt * 2 + 1) * 64 + lane], a);
        #pragma unroll
        for (int r = 0; r < 4; ++r)
            TA[(kgrp * 4 + r) * 68 + nt * 16 + (lane & 15)] = a[r];
    }
    float hn[16];
    #pragma unroll
    for (int i = 0; i < 8; ++i) hn[i] = hf[i] + TA[arow * 68 + k0 + i];
    #pragma unroll
    for (int i = 0; i < 8; ++i) hn[8 + i] = hf[8 + i] + TA[arow * 68 + 32 + k0 + i];

    if (last) {
        float v = 0.f;
        #pragma unroll
        for (int i = 0; i < 8; ++i) v += hn[i] * ro_w[k0 + i];
        #pragma unroll
        for (int i = 0; i < 8; ++i) v += hn[8 + i] * ro_w[32 + k0 + i];
        v += __shfl_xor(v, 16);
        v += __shfl_xor(v, 32);
        if (lane < 16) out[rowbase + lane] = v + ro_b[0];
        return;
    }

    *(float4*)(h + (size_t)hrow * DH + k0) = make_float4(hn[0], hn[1], hn[2], hn[3]);
    *(float4*)(h + (size_t)hrow * DH + k0 + 4) = make_float4(hn[4], hn[5], hn[6], hn[7]);
    *(float4*)(h + (size_t)hrow * DH + 32 + k0) = make_float4(hn[8], hn[9], hn[10], hn[11]);
    *(float4*)(h + (size_t)hrow * DH + 32 + k0 + 4) = make_float4(hn[12], hn[13], hn[14], hn[15]);

    Frag na0 = split8(&hn[0]), na1 = split8(&hn[8]);
    const uint4* PWtH = pack + (size_t)((l + 1) * 6 + 0) * 512;
    const uint4* PWbH = pack + (size_t)((l + 1) * 6 + 1) * 512;
    const uint4* PWtL = PWtH + LOB;
    const uint4* PWbL = PWbH + LOB;
    #pragma unroll
    for (int nt = 0; nt < 4; ++nt) {
        f32x4 s; f32x4 d;
        float b1v = b1n[nt * 16 + (lane & 15)];
        #pragma unroll
        for (int r = 0; r < 4; ++r) { s[r] = 0.f; d[r] = b1v; }
        s = mm3(na0, PWtH[(nt * 2 + 0) * 64 + lane], PWtL[(nt * 2 + 0) * 64 + lane], s);
        s = mm3(na1, PWtH[(nt * 2 + 1) * 64 + lane], PWtL[(nt * 2 + 1) * 64 + lane], s);
        d = mm3(na0, PWbH[(nt * 2 + 0) * 64 + lane], PWbL[(nt * 2 + 0) * 64 + lane], d);
        d = mm3(na1, PWbH[(nt * 2 + 1) * 64 + lane], PWbL[(nt * 2 + 1) * 64 + lane], d);
        #pragma unroll
        for (int r = 0; r < 4; ++r) {
            int rr = rowbase + kgrp * 4 + r;
            hs[(size_t)rr * DH + nt * 16 + (lane & 15)] = s[r];
            hd[(size_t)rr * DH + nt * 16 + (lane & 15)] = d[r];
        }
    }
}

extern "C" void kernel_launch(void* const* d_in, const int* in_sizes, int n_in,
                              void* d_out, int out_size, void* d_ws, size_t ws_size,
                              hipStream_t stream) {
    const float* t      = (const float*)d_in[0];
    const int*   ei     = (const int*)d_in[1];
    const float* enc_w  = (const float*)d_in[2];
    const float* enc_b  = (const float*)d_in[3];
    const float* msg1_w = (const float*)d_in[4];
    const float* msg1_b = (const float*)d_in[5];
    const float* msg2_w = (const float*)d_in[6];
    const float* msg2_b = (const float*)d_in[7];
    const float* upd1_w = (const float*)d_in[8];
    const float* upd1_b = (const float*)d_in[9];
    const float* upd2_w = (const float*)d_in[10];
    const float* upd2_b = (const float*)d_in[11];
    const float* ro_w   = (const float*)d_in[12];
    const float* ro_b   = (const float*)d_in[13];
    float* out = (float*)d_out;

    const size_t HN = (size_t)TT * NN * DH;   // 4 Mi elements
    float* h      = (float*)d_ws;                   // 16 MB
    float* hs     = h + HN;                         // 16 MB
    float* hd     = hs + HN;                        // 16 MB
    float* aggpre = hd + HN;                        // 16 MB
    uint4* pack   = (uint4*)(aggpre + HN);          // 288 KB (hi+lo)
    int* counts  = (int*)(pack + 2 * LOB);
    int* offsets = counts + NN;
    int* ssrc    = offsets + NN + 1;
    float* E1s   = (float*)(ssrc + EE);             // 128 KB
    float* E1d   = E1s + NN * DH;                   // 128 KB
    float* e0sum = E1d + NN * DH;                   // 256 B

    setup_kernel<<<84, 512, 0, stream>>>(ei, msg1_w, msg2_w, upd1_w, upd2_w,
                                         enc_w, enc_b, msg1_b,
                                         pack, counts, offsets, ssrc,
                                         E1s, E1d, e0sum);

    for (int l = 0; l < 3; ++l) {
        if (l == 0)
            agg0_kernel<<<TT * NN / 4, 256, 0, stream>>>(
                t, e0sum, E1s, E1d, offsets, ssrc, aggpre);
        else
            agg_kernel<<<TT * NN / 4, 256, 0, stream>>>(
                hs, hd, offsets, ssrc, aggpre);
        int last = (l == 2);
        upd_mfma_kernel<<<TT * NN / 64, 256, 0, stream>>>(
            h, aggpre, t, enc_w, enc_b, counts, pack, l,
            msg2_b + (size_t)l * DH, upd1_b + (size_t)l * DH,
            upd2_b + (size_t)l * DH,
            last ? msg1_b : msg1_b + (size_t)(l + 1) * DH,
            hs, hd, ro_w, ro_b, out, (l == 0) ? 1 : 0, last);
    }
}